// Round 4
// baseline (358.194 us; speedup 1.0000x reference)
//
#include <hip/hip_runtime.h>
#include <hip/hip_bf16.h>
#include <math.h>

// Problem constants
#define BATCH 8
#define NSEQ  1024
#define DIMM  768
#define NHEAD 12
#define DHEAD 64
#define SCALE 0.125f           // DHEAD^-0.5
#define ROWS  (BATCH * NSEQ)   // 8192

typedef __hip_bfloat16 bf16;
typedef __bf16 bf16x8 __attribute__((ext_vector_type(8)));
typedef float  f32x4  __attribute__((ext_vector_type(4)));

#if __has_builtin(__builtin_amdgcn_global_load_lds)
#define HAVE_GLL 1
typedef __attribute__((address_space(3))) void lds_void_t;
typedef const __attribute__((address_space(1))) void gbl_void_t;
__device__ __forceinline__ void gload16(const void* g, void* l) {
    __builtin_amdgcn_global_load_lds((gbl_void_t*)g, (lds_void_t*)l, 16, 0, 0);
}
#else
#define HAVE_GLL 0
#endif

__device__ __forceinline__ unsigned pk2(float a, float b) {
    union { unsigned u; bf16 h[2]; } x;
    x.h[0] = __float2bfloat16(a);
    x.h[1] = __float2bfloat16(b);
    return x.u;
}

// ---------------------------------------------------------------- LayerNorm (fp32 in, bf16 out)
__global__ __launch_bounds__(256) void ln_kernel(const float* __restrict__ x,
                                                 const float* __restrict__ g,
                                                 const float* __restrict__ bta,
                                                 bf16* __restrict__ y) {
    __shared__ float ps[4], pq[4];
    __shared__ float mean_s, rstd_s;
    int row = blockIdx.x;
    int tid = threadIdx.x;
    const float* xr = x + (size_t)row * DIMM;
    float v[3];
    float s = 0.f, sq = 0.f;
#pragma unroll
    for (int i = 0; i < 3; ++i) {
        v[i] = xr[tid + 256 * i];
        s += v[i];
        sq += v[i] * v[i];
    }
#pragma unroll
    for (int off = 32; off >= 1; off >>= 1) {
        s  += __shfl_down(s, off);
        sq += __shfl_down(sq, off);
    }
    int wid = tid >> 6, lane = tid & 63;
    if (lane == 0) { ps[wid] = s; pq[wid] = sq; }
    __syncthreads();
    if (tid == 0) {
        float S = ps[0] + ps[1] + ps[2] + ps[3];
        float Q = pq[0] + pq[1] + pq[2] + pq[3];
        float mean = S * (1.0f / DIMM);
        float var  = Q * (1.0f / DIMM) - mean * mean;
        mean_s = mean;
        rstd_s = rsqrtf(fmaxf(var, 0.f) + 1e-5f);
    }
    __syncthreads();
    float mean = mean_s, rstd = rstd_s;
    bf16* yr = y + (size_t)row * DIMM;
#pragma unroll
    for (int i = 0; i < 3; ++i) {
        int c = tid + 256 * i;
        yr[c] = __float2bfloat16((v[i] - mean) * rstd * g[c] + bta[c]);
    }
}

// ------------------------------------------- transpose + fp32->bf16: Wt[n][k] = W[k][n]
__global__ __launch_bounds__(256) void transpose_bf16(const float* __restrict__ W,
                                                      bf16* __restrict__ Wt,
                                                      int K, int N) {
    __shared__ float t[32][33];
    int n0 = blockIdx.x * 32, k0 = blockIdx.y * 32;
    int tx = threadIdx.x, ty = threadIdx.y;   // 32, 8
#pragma unroll
    for (int i = 0; i < 32; i += 8)
        t[ty + i][tx] = W[(size_t)(k0 + ty + i) * N + n0 + tx];
    __syncthreads();
#pragma unroll
    for (int i = 0; i < 32; i += 8)
        Wt[(size_t)(n0 + ty + i) * K + k0 + tx] = __float2bfloat16(t[tx][ty + i]);
}

// ------------------------------------------------------- bf16 MFMA GEMM (m97 structure)
// C[M,Nn] = A[M,K] @ Bt[Nn,K]^T (+bias). 128x128 tile, BK=32, global_load_lds staging.
template <bool OUT_BF16>
__global__ __launch_bounds__(256) void gemm_mfma(const bf16* __restrict__ A,
                                                 const bf16* __restrict__ Bt,
                                                 const float* __restrict__ bias,
                                                 void* __restrict__ Cv,
                                                 int M, int Nn, int K) {
    __shared__ bf16 As[128][32];   // unpadded: lane-linear for global_load_lds
    __shared__ bf16 Bs[128][32];
    int tid = threadIdx.x;
    int wave = tid >> 6, lane = tid & 63, quad = lane >> 4, l16 = lane & 15;
    int wm = (wave >> 1) * 64, wn = (wave & 1) * 64;
    int m0 = blockIdx.y * 128, n0 = blockIdx.x * 128;

    f32x4 acc[4][4] = {};

#if HAVE_GLL
    const char* Ag = (const char*)(A  + (size_t)(m0 + (tid >> 2)) * K + (tid & 3) * 8);
    const char* Bg = (const char*)(Bt + (size_t)(n0 + (tid >> 2)) * K + (tid & 3) * 8);
    char* AsB = (char*)&As[0][0] + tid * 16;
    char* BsB = (char*)&Bs[0][0] + tid * 16;
    const size_t radv = (size_t)64 * K * 2;   // +64 rows

    for (int k0 = 0; k0 < K; k0 += 32) {
        __syncthreads();              // previous tile's frag reads done
        gload16(Ag, AsB);
        gload16(Ag + radv, AsB + 4096);
        gload16(Bg, BsB);
        gload16(Bg + radv, BsB + 4096);
        Ag += 64; Bg += 64;           // 32 bf16
        __syncthreads();              // drains vmcnt -> LDS visible
#else
    int srow = tid >> 1;
    int sk = (tid & 1) * 16;
    const bf16* Ap = A  + (size_t)(m0 + srow) * K + sk;
    const bf16* Bp = Bt + (size_t)(n0 + srow) * K + sk;
    for (int k0 = 0; k0 < K; k0 += 32) {
        uint4 a0 = *(const uint4*)(Ap + k0);
        uint4 a1 = *(const uint4*)(Ap + k0 + 8);
        uint4 b0 = *(const uint4*)(Bp + k0);
        uint4 b1 = *(const uint4*)(Bp + k0 + 8);
        __syncthreads();
        *(uint4*)&As[srow][sk]     = a0;
        *(uint4*)&As[srow][sk + 8] = a1;
        *(uint4*)&Bs[srow][sk]     = b0;
        *(uint4*)&Bs[srow][sk + 8] = b1;
        __syncthreads();
#endif
        bf16x8 af[4], bf_[4];
#pragma unroll
        for (int i = 0; i < 4; ++i) {
            af[i]  = *(const bf16x8*)&As[wm + i * 16 + l16][quad * 8];
            bf_[i] = *(const bf16x8*)&Bs[wn + i * 16 + l16][quad * 8];
        }
#pragma unroll
        for (int mi = 0; mi < 4; ++mi)
#pragma unroll
            for (int ni = 0; ni < 4; ++ni)
                acc[mi][ni] = __builtin_amdgcn_mfma_f32_16x16x32_bf16(
                    af[mi], bf_[ni], acc[mi][ni], 0, 0, 0);
    }

    float bv[4] = {0.f, 0.f, 0.f, 0.f};
    if (!OUT_BF16 && bias) {
#pragma unroll
        for (int ni = 0; ni < 4; ++ni) bv[ni] = bias[n0 + wn + ni * 16 + l16];
    }
#pragma unroll
    for (int mi = 0; mi < 4; ++mi)
#pragma unroll
        for (int reg = 0; reg < 4; ++reg) {
            size_t row = m0 + wm + mi * 16 + quad * 4 + reg;
#pragma unroll
            for (int ni = 0; ni < 4; ++ni) {
                int col = n0 + wn + ni * 16 + l16;
                float val = acc[mi][ni][reg] + bv[ni];
                if (OUT_BF16)
                    ((bf16*)Cv)[row * Nn + col] = __float2bfloat16(val);
                else
                    ((float*)Cv)[row * Nn + col] = val;
            }
        }
}

// ------------------------------------------------- MFMA flash attention (S^T form)
// S^T = K·Q^T via mfma(A=K-frag(global), B=Q-frag(regs)); softmax per-lane over k;
// P^T -> A-layout via per-wave LDS b64 pack; V^T staged in swizzled LDS.
// qkv: [ROWS, 2304] bf16. rpb: [NHEAD, NSEQ, NSEQ] fp32. outb: [ROWS, DIMM] bf16.
__global__ __launch_bounds__(256, 5) void attn_mfma(const bf16* __restrict__ qkv,
                                                    const float* __restrict__ rpb,
                                                    bf16* __restrict__ outb) {
    __shared__ unsigned Vt32[64][36];   // V^T rows d=0..63, dword cols = k-pairs, XOR-swizzled blocks
    __shared__ bf16 Ps[4][16][72];      // per-wave P (A-layout): row q, col k; stride 72 (16B-mult)

    int tid = threadIdx.x;
    int wave = tid >> 6, lane = tid & 63, quad = lane >> 4, l16 = lane & 15;
    int bid = blockIdx.x;
    int b  = bid & 7;                   // batch innermost: 8 blocks share rpb stripe
    int r2 = bid >> 3;
    int h  = r2 % NHEAD;
    int mt = r2 / NHEAD;
    int m0 = mt * 64;

    // Q B-fragments in registers for the whole kernel (wave owns q rows wave*16..+16; n-index=l16)
    const bf16* qrow = qkv + (size_t)(b * NSEQ + m0 + wave * 16 + l16) * (3 * DIMM) + h * DHEAD;
    bf16x8 qf0 = *(const bf16x8*)(qrow + quad * 8);
    bf16x8 qf1 = *(const bf16x8*)(qrow + 32 + quad * 8);

    // rpb row for this lane's q (= l16)
    const float* rp = rpb + ((size_t)h * NSEQ + (m0 + wave * 16 + l16)) * NSEQ;

    // K A-frag base: row = l16 within each 16-row k-subtile
    const bf16* kg = qkv + (size_t)(b * NSEQ + l16) * (3 * DIMM) + DIMM + h * DHEAD + quad * 8;

    // V loader: thread owns 2 adjacent k-rows x 8 d-cols
    int vk = (tid >> 3) * 2;            // 0..62 even
    int vd = (tid & 7) * 8;             // 0..56
    int vkp = tid >> 3;                 // logical dword col (k-pair)
    const bf16* vg = qkv + (size_t)(b * NSEQ + vk) * (3 * DIMM) + 2 * DIMM + h * DHEAD + vd;
    uint4 va = *(const uint4*)(vg);
    uint4 vb = *(const uint4*)(vg + 3 * DIMM);

    float m_s = -INFINITY, l_s = 0.f;
    f32x4 acco[4] = {};

    // stored-block swizzle: logical dword col c of row r lives at ((c>>2)^((r>>3)&7))<<2 | (c&3)
    int wblk = ((vkp >> 2) ^ (vd >> 3)) << 2 | (vkp & 3);   // (vd+j)>>3 == vd>>3 for j<8

    for (int kt = 0; kt < 16; ++kt) {
        __syncthreads();                // previous iteration's Vt reads done
        {
            union { uint4 q; unsigned short u[8]; } A_, B_;
            A_.q = va; B_.q = vb;
#pragma unroll
            for (int j = 0; j < 8; ++j)
                Vt32[vd + j][wblk] = (unsigned)A_.u[j] | ((unsigned)B_.u[j] << 16);
        }
        __syncthreads();

        // prefetch next V tile
        if (kt + 1 < 16) {
            const bf16* v2 = vg + (size_t)(kt + 1) * 64 * (3 * DIMM);
            va = *(const uint4*)(v2);
            vb = *(const uint4*)(v2 + 3 * DIMM);
        }

        // rpb: float4 per t (k fast axis)
        float4 rv[4];
        const float* rpk = rp + kt * 64;
#pragma unroll
        for (int t = 0; t < 4; ++t)
            rv[t] = *(const float4*)&rpk[t * 16 + quad * 4];

        // ---- S^T = K Q^T : accs[t][r] = S[q=l16][k = kt*64 + t*16 + quad*4 + r]
        f32x4 accs[4] = {};
#pragma unroll
        for (int t = 0; t < 4; ++t) {
            const bf16* kr = kg + (size_t)(kt * 64 + t * 16) * (3 * DIMM);
            bf16x8 kf0 = *(const bf16x8*)(kr);
            bf16x8 kf1 = *(const bf16x8*)(kr + 32);
            accs[t] = __builtin_amdgcn_mfma_f32_16x16x32_bf16(kf0, qf0, accs[t], 0, 0, 0);
            accs[t] = __builtin_amdgcn_mfma_f32_16x16x32_bf16(kf1, qf1, accs[t], 0, 0, 0);
        }

        // ---- softmax over k (in-register + 2 shuffles across quads)
        float mx = -INFINITY;
        {
            float rb[4][4] = {{rv[0].x, rv[0].y, rv[0].z, rv[0].w},
                              {rv[1].x, rv[1].y, rv[1].z, rv[1].w},
                              {rv[2].x, rv[2].y, rv[2].z, rv[2].w},
                              {rv[3].x, rv[3].y, rv[3].z, rv[3].w}};
#pragma unroll
            for (int t = 0; t < 4; ++t)
#pragma unroll
                for (int r = 0; r < 4; ++r) {
                    accs[t][r] = fmaf(accs[t][r], SCALE, rb[t][r]);
                    mx = fmaxf(mx, accs[t][r]);
                }
        }
        mx = fmaxf(mx, __shfl_xor(mx, 16));
        mx = fmaxf(mx, __shfl_xor(mx, 32));
        float mn = fmaxf(m_s, mx);
        float alpha = __expf(m_s - mn);
        m_s = mn;
        float sum = 0.f;
#pragma unroll
        for (int t = 0; t < 4; ++t)
#pragma unroll
            for (int r = 0; r < 4; ++r) {
                float p = __expf(accs[t][r] - mn);
                accs[t][r] = p;
                sum += p;
            }
        sum += __shfl_xor(sum, 16);
        sum += __shfl_xor(sum, 32);
        l_s = l_s * alpha + sum;

        // ---- rescale O (alpha for q = quad*4+r via bpermute from quad-0 lanes)
        float ab[4];
#pragma unroll
        for (int r = 0; r < 4; ++r) ab[r] = __shfl(alpha, quad * 4 + r);
#pragma unroll
        for (int dt = 0; dt < 4; ++dt)
#pragma unroll
            for (int r = 0; r < 4; ++r) acco[dt][r] *= ab[r];

        // ---- P^T -> Ps (A-layout): row q=l16, cols k (4 consecutive per lane per t)
#pragma unroll
        for (int t = 0; t < 4; ++t) {
            uint2 w;
            w.x = pk2(accs[t][0], accs[t][1]);
            w.y = pk2(accs[t][2], accs[t][3]);
            *(uint2*)&Ps[wave][l16][t * 16 + quad * 4] = w;
        }
        __asm__ volatile("s_waitcnt lgkmcnt(0)" ::: "memory");

        // ---- O += P V  (A=P-frag from Ps, B=V^T-frag from swizzled Vt)
#pragma unroll
        for (int s = 0; s < 2; ++s) {
            bf16x8 pf = *(const bf16x8*)&Ps[wave][l16][s * 32 + quad * 8];
#pragma unroll
            for (int dt = 0; dt < 4; ++dt) {
                int row = dt * 16 + l16;
                int sblk = ((s * 4 + quad) ^ ((row >> 3) & 7)) << 2;
                bf16x8 vf = *(const bf16x8*)&Vt32[row][sblk];
                acco[dt] = __builtin_amdgcn_mfma_f32_16x16x32_bf16(pf, vf, acco[dt], 0, 0, 0);
            }
        }
    }

    // ---- epilogue: O / l (l for q=quad*4+r via shuffle), bf16 store
    float invl[4];
#pragma unroll
    for (int r = 0; r < 4; ++r) invl[r] = 1.f / __shfl(l_s, quad * 4 + r);
    bf16* orow = outb + (size_t)(b * NSEQ + m0 + wave * 16) * DIMM + h * DHEAD;
#pragma unroll
    for (int dt = 0; dt < 4; ++dt)
#pragma unroll
        for (int r = 0; r < 4; ++r)
            orow[(size_t)(quad * 4 + r) * DIMM + dt * 16 + l16] =
                __float2bfloat16(acco[dt][r] * invl[r]);
}

// ---------------------------------------------------------------- launch
extern "C" void kernel_launch(void* const* d_in, const int* in_sizes, int n_in,
                              void* d_out, int out_size, void* d_ws, size_t ws_size,
                              hipStream_t stream) {
    const float* x     = (const float*)d_in[0];
    const float* rpb   = (const float*)d_in[1];
    const float* W_qkv = (const float*)d_in[2];
    const float* W_out = (const float*)d_in[3];
    const float* b_out = (const float*)d_in[4];
    const float* ln_g  = (const float*)d_in[5];
    const float* ln_b  = (const float*)d_in[6];
    float* out = (float*)d_out;

    char* p = (char*)d_ws;
    bf16* xn    = (bf16*)p; p += (size_t)ROWS * DIMM * 2;
    bf16* qkv   = (bf16*)p; p += (size_t)ROWS * 3 * DIMM * 2;
    bf16* attn  = (bf16*)p; p += (size_t)ROWS * DIMM * 2;
    bf16* WqkvT = (bf16*)p; p += (size_t)3 * DIMM * DIMM * 2;
    bf16* WoutT = (bf16*)p; p += (size_t)DIMM * DIMM * 2;

    ln_kernel<<<ROWS, 256, 0, stream>>>(x, ln_g, ln_b, xn);
    transpose_bf16<<<dim3(3 * DIMM / 32, DIMM / 32), dim3(32, 8), 0, stream>>>(
        W_qkv, WqkvT, DIMM, 3 * DIMM);
    transpose_bf16<<<dim3(DIMM / 32, DIMM / 32), dim3(32, 8), 0, stream>>>(
        W_out, WoutT, DIMM, DIMM);

    gemm_mfma<true><<<dim3(3 * DIMM / 128, ROWS / 128), 256, 0, stream>>>(
        xn, WqkvT, nullptr, qkv, ROWS, 3 * DIMM, DIMM);

    attn_mfma<<<BATCH * NHEAD * (NSEQ / 64), 256, 0, stream>>>(qkv, rpb, attn);

    gemm_mfma<false><<<dim3(DIMM / 128, ROWS / 128), 256, 0, stream>>>(
        attn, WoutT, b_out, out, ROWS, DIMM, DIMM);
}

// Round 5
// 286.520 us; speedup vs baseline: 1.2502x; 1.2502x over previous
//
#include <hip/hip_runtime.h>
#include <hip/hip_bf16.h>
#include <math.h>

// Problem constants
#define BATCH 8
#define NSEQ  1024
#define DIMM  768
#define NHEAD 12
#define DHEAD 64
#define SCALE 0.125f           // DHEAD^-0.5
#define ROWS  (BATCH * NSEQ)   // 8192

typedef __hip_bfloat16 bf16;
typedef __bf16 bf16x8 __attribute__((ext_vector_type(8)));
typedef float  f32x4  __attribute__((ext_vector_type(4)));

#if __has_builtin(__builtin_amdgcn_global_load_lds)
#define HAVE_GLL 1
typedef __attribute__((address_space(3))) void lds_void_t;
typedef const __attribute__((address_space(1))) void gbl_void_t;
__device__ __forceinline__ void gload16(const void* g, void* l) {
    __builtin_amdgcn_global_load_lds((gbl_void_t*)g, (lds_void_t*)l, 16, 0, 0);
}
#else
#define HAVE_GLL 0
#endif

__device__ __forceinline__ unsigned pk2(float a, float b) {
    union { unsigned u; bf16 h[2]; } x;
    x.h[0] = __float2bfloat16(a);
    x.h[1] = __float2bfloat16(b);
    return x.u;
}

// ---------------------------------------------------------------- LayerNorm (fp32 in, bf16 out)
__global__ __launch_bounds__(256) void ln_kernel(const float* __restrict__ x,
                                                 const float* __restrict__ g,
                                                 const float* __restrict__ bta,
                                                 bf16* __restrict__ y) {
    __shared__ float ps[4], pq[4];
    __shared__ float mean_s, rstd_s;
    int row = blockIdx.x;
    int tid = threadIdx.x;
    const float* xr = x + (size_t)row * DIMM;
    float v[3];
    float s = 0.f, sq = 0.f;
#pragma unroll
    for (int i = 0; i < 3; ++i) {
        v[i] = xr[tid + 256 * i];
        s += v[i];
        sq += v[i] * v[i];
    }
#pragma unroll
    for (int off = 32; off >= 1; off >>= 1) {
        s  += __shfl_down(s, off);
        sq += __shfl_down(sq, off);
    }
    int wid = tid >> 6, lane = tid & 63;
    if (lane == 0) { ps[wid] = s; pq[wid] = sq; }
    __syncthreads();
    if (tid == 0) {
        float S = ps[0] + ps[1] + ps[2] + ps[3];
        float Q = pq[0] + pq[1] + pq[2] + pq[3];
        float mean = S * (1.0f / DIMM);
        float var  = Q * (1.0f / DIMM) - mean * mean;
        mean_s = mean;
        rstd_s = rsqrtf(fmaxf(var, 0.f) + 1e-5f);
    }
    __syncthreads();
    float mean = mean_s, rstd = rstd_s;
    bf16* yr = y + (size_t)row * DIMM;
#pragma unroll
    for (int i = 0; i < 3; ++i) {
        int c = tid + 256 * i;
        yr[c] = __float2bfloat16((v[i] - mean) * rstd * g[c] + bta[c]);
    }
}

// ------------------------------------------- transpose + fp32->bf16: Wt[n][k] = W[k][n]
__global__ __launch_bounds__(256) void transpose_bf16(const float* __restrict__ W,
                                                      bf16* __restrict__ Wt,
                                                      int K, int N) {
    __shared__ float t[32][33];
    int n0 = blockIdx.x * 32, k0 = blockIdx.y * 32;
    int tx = threadIdx.x, ty = threadIdx.y;   // 32, 8
#pragma unroll
    for (int i = 0; i < 32; i += 8)
        t[ty + i][tx] = W[(size_t)(k0 + ty + i) * N + n0 + tx];
    __syncthreads();
#pragma unroll
    for (int i = 0; i < 32; i += 8)
        Wt[(size_t)(n0 + ty + i) * K + k0 + tx] = __float2bfloat16(t[tx][ty + i]);
}

// ------------------------------------------------------- bf16 MFMA GEMM (m97 structure)
// C[M,Nn] = A[M,K] @ Bt[Nn,K]^T (+bias). 128x128 tile, BK=32, global_load_lds staging.
template <bool OUT_BF16>
__global__ __launch_bounds__(256) void gemm_mfma(const bf16* __restrict__ A,
                                                 const bf16* __restrict__ Bt,
                                                 const float* __restrict__ bias,
                                                 void* __restrict__ Cv,
                                                 int M, int Nn, int K) {
    __shared__ bf16 As[128][32];   // unpadded: lane-linear for global_load_lds
    __shared__ bf16 Bs[128][32];
    int tid = threadIdx.x;
    int wave = tid >> 6, lane = tid & 63, quad = lane >> 4, l16 = lane & 15;
    int wm = (wave >> 1) * 64, wn = (wave & 1) * 64;
    int m0 = blockIdx.y * 128, n0 = blockIdx.x * 128;

    f32x4 acc[4][4] = {};

#if HAVE_GLL
    const char* Ag = (const char*)(A  + (size_t)(m0 + (tid >> 2)) * K + (tid & 3) * 8);
    const char* Bg = (const char*)(Bt + (size_t)(n0 + (tid >> 2)) * K + (tid & 3) * 8);
    char* AsB = (char*)&As[0][0] + tid * 16;
    char* BsB = (char*)&Bs[0][0] + tid * 16;
    const size_t radv = (size_t)64 * K * 2;   // +64 rows

    for (int k0 = 0; k0 < K; k0 += 32) {
        __syncthreads();              // previous tile's frag reads done
        gload16(Ag, AsB);
        gload16(Ag + radv, AsB + 4096);
        gload16(Bg, BsB);
        gload16(Bg + radv, BsB + 4096);
        Ag += 64; Bg += 64;           // 32 bf16
        __syncthreads();              // drains vmcnt -> LDS visible
#else
    int srow = tid >> 1;
    int sk = (tid & 1) * 16;
    const bf16* Ap = A  + (size_t)(m0 + srow) * K + sk;
    const bf16* Bp = Bt + (size_t)(n0 + srow) * K + sk;
    for (int k0 = 0; k0 < K; k0 += 32) {
        uint4 a0 = *(const uint4*)(Ap + k0);
        uint4 a1 = *(const uint4*)(Ap + k0 + 8);
        uint4 b0 = *(const uint4*)(Bp + k0);
        uint4 b1 = *(const uint4*)(Bp + k0 + 8);
        __syncthreads();
        *(uint4*)&As[srow][sk]     = a0;
        *(uint4*)&As[srow][sk + 8] = a1;
        *(uint4*)&Bs[srow][sk]     = b0;
        *(uint4*)&Bs[srow][sk + 8] = b1;
        __syncthreads();
#endif
        bf16x8 af[4], bf_[4];
#pragma unroll
        for (int i = 0; i < 4; ++i) {
            af[i]  = *(const bf16x8*)&As[wm + i * 16 + l16][quad * 8];
            bf_[i] = *(const bf16x8*)&Bs[wn + i * 16 + l16][quad * 8];
        }
#pragma unroll
        for (int mi = 0; mi < 4; ++mi)
#pragma unroll
            for (int ni = 0; ni < 4; ++ni)
                acc[mi][ni] = __builtin_amdgcn_mfma_f32_16x16x32_bf16(
                    af[mi], bf_[ni], acc[mi][ni], 0, 0, 0);
    }

    float bv[4] = {0.f, 0.f, 0.f, 0.f};
    if (!OUT_BF16 && bias) {
#pragma unroll
        for (int ni = 0; ni < 4; ++ni) bv[ni] = bias[n0 + wn + ni * 16 + l16];
    }
#pragma unroll
    for (int mi = 0; mi < 4; ++mi)
#pragma unroll
        for (int reg = 0; reg < 4; ++reg) {
            size_t row = m0 + wm + mi * 16 + quad * 4 + reg;
#pragma unroll
            for (int ni = 0; ni < 4; ++ni) {
                int col = n0 + wn + ni * 16 + l16;
                float val = acc[mi][ni][reg] + bv[ni];
                if (OUT_BF16)
                    ((bf16*)Cv)[row * Nn + col] = __float2bfloat16(val);
                else
                    ((float*)Cv)[row * Nn + col] = val;
            }
        }
}

// ------------------------------------------------- MFMA flash attention (S^T form, dbuf)
// S^T = K·Q^T; K staged via global_load_lds (dbuf), V staged transposed+swizzled (dbuf);
// softmax per-lane over k; P^T -> A-layout via per-wave LDS b64 pack.
// qkv: [ROWS, 2304] bf16. rpb: [NHEAD, NSEQ, NSEQ] fp32. outb: [ROWS, DIMM] bf16.
#define KTILEB (64 * 3 * DIMM * 2)   // bytes per 64-row k-tile step in qkv

__global__ __launch_bounds__(256, 4) void attn_mfma(const bf16* __restrict__ qkv,
                                                    const float* __restrict__ rpb,
                                                    bf16* __restrict__ outb) {
    __shared__ char KsRaw[2][8192];     // [buf][t*2048 + s*1024 + (quad*16+l16)*16]
    __shared__ unsigned Vt32[2][64][36];// [buf][d][k-pair dword], XOR-swizzled blocks
    __shared__ bf16 Ps[4][16][72];      // per-wave P (A-layout): row q, col k

    int tid = threadIdx.x;
    int wave = tid >> 6, lane = tid & 63, quad = lane >> 4, l16 = lane & 15;
    int bid = blockIdx.x;
    int b  = bid & 7;                   // batch innermost: 8 blocks share rpb stripe
    int r2 = bid >> 3;
    int h  = r2 % NHEAD;
    int mt = r2 / NHEAD;
    int m0 = mt * 64;

    // Q B-fragments in registers (wave owns q rows wave*16..+16; n-index = l16)
    const bf16* qrow = qkv + (size_t)(b * NSEQ + m0 + wave * 16 + l16) * (3 * DIMM) + h * DHEAD;
    bf16x8 qf0 = *(const bf16x8*)(qrow + quad * 8);
    bf16x8 qf1 = *(const bf16x8*)(qrow + 32 + quad * 8);

    // rpb row for this lane's q (= l16)
    const float* rp = rpb + ((size_t)h * NSEQ + (m0 + wave * 16 + l16)) * NSEQ;

#if HAVE_GLL
    // K staging: wave w stages k-subtile t=w, rows w*16+l16, col chunk quad*8 (+i*32)
    const char* kgl = (const char*)(qkv + (size_t)(b * NSEQ + wave * 16 + l16) * (3 * DIMM)
                                    + DIMM + h * DHEAD + quad * 8);
    char* kdst = &KsRaw[0][0] + tid * 16 + wave * 1024;   // +buf*8192, +i*1024
#else
    // fallback: coalesced reg staging (row tid>>2, 16-col chunk (tid&3)*16)
    int ksr = tid >> 2, ksd = (tid & 3) * 16;
    const bf16* kgf = qkv + (size_t)(b * NSEQ + ksr) * (3 * DIMM) + DIMM + h * DHEAD + ksd;
#endif

    // V loader: thread owns 2 adjacent k-rows x 8 d-cols
    int vk = (tid >> 3) * 2;            // 0..62 even
    int vd = (tid & 7) * 8;             // 0..56
    int vkp = tid >> 3;                 // logical dword col (k-pair)
    const bf16* vg = qkv + (size_t)(b * NSEQ + vk) * (3 * DIMM) + 2 * DIMM + h * DHEAD + vd;
    int wblk = (((vkp >> 2) ^ (vd >> 3)) << 2) | (vkp & 3);

    float m_s = -INFINITY, l_s = 0.f;
    f32x4 acco[4] = {};

    // ---------------- preload tile 0
#if HAVE_GLL
    gload16(kgl, kdst);
    gload16(kgl + 64, kdst + 1024);
#endif
    uint4 va = *(const uint4*)(vg);
    uint4 vb = *(const uint4*)(vg + 3 * DIMM);
#if !HAVE_GLL
    {
        uint4 k0v = *(const uint4*)(kgf);
        uint4 k1v = *(const uint4*)(kgf + 8);
        bf16* kb = (bf16*)(&KsRaw[0][0] + (ksr >> 4) * 2048 + ((ksr & 15)) * 16);
        // store 16 cols: chunk s = ksd/32, within-chunk quad = (ksd%32)/8
        char* d0 = &KsRaw[0][0] + (ksr >> 4) * 2048 + (ksd >> 5) * 1024 + ((((ksd >> 3) & 3) * 16 + (ksr & 15)) * 16);
        *(uint4*)d0 = k0v;
        char* d1 = &KsRaw[0][0] + (ksr >> 4) * 2048 + ((ksd + 8) >> 5) * 1024 + (((((ksd + 8) >> 3) & 3) * 16 + (ksr & 15)) * 16);
        *(uint4*)d1 = k1v;
        (void)kb;
    }
#endif
    {
        union { uint4 q; unsigned short u[8]; } A_, B_;
        A_.q = va; B_.q = vb;
#pragma unroll
        for (int j = 0; j < 8; ++j)
            Vt32[0][vd + j][wblk] = (unsigned)A_.u[j] | ((unsigned)B_.u[j] << 16);
    }
    __syncthreads();   // drains gll vmcnt + ds writes

    for (int kt = 0; kt < 16; ++kt) {
        int cur = kt & 1, nxt = cur ^ 1;

        // ---- prefetch next tile (K -> LDS[nxt] async, V -> regs)
        if (kt + 1 < 16) {
#if HAVE_GLL
            const char* kg2 = kgl + (size_t)(kt + 1) * KTILEB;
            gload16(kg2, kdst + nxt * 8192);
            gload16(kg2 + 64, kdst + nxt * 8192 + 1024);
#endif
            const bf16* v2 = vg + (size_t)(kt + 1) * 64 * (3 * DIMM);
            va = *(const uint4*)(v2);
            vb = *(const uint4*)(v2 + 3 * DIMM);
        }

        // ---- rpb: float4 per t (k fast axis)
        float4 rv[4];
        const float* rpk = rp + kt * 64;
#pragma unroll
        for (int t = 0; t < 4; ++t)
            rv[t] = *(const float4*)&rpk[t * 16 + quad * 4];

        // ---- S^T = K Q^T : accs[t][r] = S[q=l16][k = kt*64 + t*16 + quad*4 + r]
        f32x4 accs[4] = {};
#pragma unroll
        for (int t = 0; t < 4; ++t) {
            const char* kb = &KsRaw[cur][0] + t * 2048 + (quad * 16 + l16) * 16;
            bf16x8 kf0 = *(const bf16x8*)(kb);
            bf16x8 kf1 = *(const bf16x8*)(kb + 1024);
            accs[t] = __builtin_amdgcn_mfma_f32_16x16x32_bf16(kf0, qf0, accs[t], 0, 0, 0);
            accs[t] = __builtin_amdgcn_mfma_f32_16x16x32_bf16(kf1, qf1, accs[t], 0, 0, 0);
        }

        // ---- softmax over k (in-register + 2 shuffles across quads)
        float mx = -INFINITY;
        {
            float rb[4][4] = {{rv[0].x, rv[0].y, rv[0].z, rv[0].w},
                              {rv[1].x, rv[1].y, rv[1].z, rv[1].w},
                              {rv[2].x, rv[2].y, rv[2].z, rv[2].w},
                              {rv[3].x, rv[3].y, rv[3].z, rv[3].w}};
#pragma unroll
            for (int t = 0; t < 4; ++t)
#pragma unroll
                for (int r = 0; r < 4; ++r) {
                    accs[t][r] = fmaf(accs[t][r], SCALE, rb[t][r]);
                    mx = fmaxf(mx, accs[t][r]);
                }
        }
        mx = fmaxf(mx, __shfl_xor(mx, 16));
        mx = fmaxf(mx, __shfl_xor(mx, 32));
        float mn = fmaxf(m_s, mx);
        float alpha = __expf(m_s - mn);
        m_s = mn;
        float sum = 0.f;
#pragma unroll
        for (int t = 0; t < 4; ++t)
#pragma unroll
            for (int r = 0; r < 4; ++r) {
                float p = __expf(accs[t][r] - mn);
                accs[t][r] = p;
                sum += p;
            }
        sum += __shfl_xor(sum, 16);
        sum += __shfl_xor(sum, 32);
        l_s = l_s * alpha + sum;

        // ---- rescale O (alpha for q = quad*4+r from lane with l16 = quad*4+r)
        float ab[4];
#pragma unroll
        for (int r = 0; r < 4; ++r) ab[r] = __shfl(alpha, quad * 4 + r);
#pragma unroll
        for (int dt = 0; dt < 4; ++dt)
#pragma unroll
            for (int r = 0; r < 4; ++r) acco[dt][r] *= ab[r];

        // ---- P^T -> Ps (A-layout): row q=l16, cols k (4 consecutive per lane per t)
#pragma unroll
        for (int t = 0; t < 4; ++t) {
            uint2 w;
            w.x = pk2(accs[t][0], accs[t][1]);
            w.y = pk2(accs[t][2], accs[t][3]);
            *(uint2*)&Ps[wave][l16][t * 16 + quad * 4] = w;
        }
        __asm__ volatile("s_waitcnt lgkmcnt(0)" ::: "memory");

        // ---- O += P V  (A=P-frag from Ps, B=V^T-frag from swizzled Vt[cur])
#pragma unroll
        for (int s = 0; s < 2; ++s) {
            bf16x8 pf = *(const bf16x8*)&Ps[wave][l16][s * 32 + quad * 8];
#pragma unroll
            for (int dt = 0; dt < 4; ++dt) {
                int row = dt * 16 + l16;
                int sblk = (((s * 4 + quad) ^ ((row >> 3) & 7)) << 2);
                bf16x8 vf = *(const bf16x8*)&Vt32[cur][row][sblk];
                acco[dt] = __builtin_amdgcn_mfma_f32_16x16x32_bf16(pf, vf, acco[dt], 0, 0, 0);
            }
        }

        // ---- stage prefetched V into Vt[nxt]
        if (kt + 1 < 16) {
            union { uint4 q; unsigned short u[8]; } A_, B_;
            A_.q = va; B_.q = vb;
#pragma unroll
            for (int j = 0; j < 8; ++j)
                Vt32[nxt][vd + j][wblk] = (unsigned)A_.u[j] | ((unsigned)B_.u[j] << 16);
        }
        __syncthreads();   // K[nxt] gll drained; V[nxt] visible; cur reads done
    }

    // ---- epilogue: O / l (l for q=quad*4+r via shuffle), bf16 store
    float invl[4];
#pragma unroll
    for (int r = 0; r < 4; ++r) invl[r] = 1.f / __shfl(l_s, quad * 4 + r);
    bf16* orow = outb + (size_t)(b * NSEQ + m0 + wave * 16) * DIMM + h * DHEAD;
#pragma unroll
    for (int dt = 0; dt < 4; ++dt)
#pragma unroll
        for (int r = 0; r < 4; ++r)
            orow[(size_t)(quad * 4 + r) * DIMM + dt * 16 + l16] =
                __float2bfloat16(acco[dt][r] * invl[r]);
}

// ---------------------------------------------------------------- launch
extern "C" void kernel_launch(void* const* d_in, const int* in_sizes, int n_in,
                              void* d_out, int out_size, void* d_ws, size_t ws_size,
                              hipStream_t stream) {
    const float* x     = (const float*)d_in[0];
    const float* rpb   = (const float*)d_in[1];
    const float* W_qkv = (const float*)d_in[2];
    const float* W_out = (const float*)d_in[3];
    const float* b_out = (const float*)d_in[4];
    const float* ln_g  = (const float*)d_in[5];
    const float* ln_b  = (const float*)d_in[6];
    float* out = (float*)d_out;

    char* p = (char*)d_ws;
    bf16* xn    = (bf16*)p; p += (size_t)ROWS * DIMM * 2;
    bf16* qkv   = (bf16*)p; p += (size_t)ROWS * 3 * DIMM * 2;
    bf16* attn  = (bf16*)p; p += (size_t)ROWS * DIMM * 2;
    bf16* WqkvT = (bf16*)p; p += (size_t)3 * DIMM * DIMM * 2;
    bf16* WoutT = (bf16*)p; p += (size_t)DIMM * DIMM * 2;

    ln_kernel<<<ROWS, 256, 0, stream>>>(x, ln_g, ln_b, xn);
    transpose_bf16<<<dim3(3 * DIMM / 32, DIMM / 32), dim3(32, 8), 0, stream>>>(
        W_qkv, WqkvT, DIMM, 3 * DIMM);
    transpose_bf16<<<dim3(DIMM / 32, DIMM / 32), dim3(32, 8), 0, stream>>>(
        W_out, WoutT, DIMM, DIMM);

    gemm_mfma<true><<<dim3(3 * DIMM / 128, ROWS / 128), 256, 0, stream>>>(
        xn, WqkvT, nullptr, qkv, ROWS, 3 * DIMM, DIMM);

    attn_mfma<<<BATCH * NHEAD * (NSEQ / 64), 256, 0, stream>>>(qkv, rpb, attn);

    gemm_mfma<false><<<dim3(DIMM / 128, ROWS / 128), 256, 0, stream>>>(
        attn, WoutT, b_out, out, ROWS, DIMM, DIMM);
}